// Round 7
// baseline (357.838 us; speedup 1.0000x reference)
//
#include <hip/hip_runtime.h>
#include <hip/hip_bf16.h>
#include <cstdint>
#include <cstddef>

// Problem constants
#define B_ 4
#define L_ 4096
#define D_ 1024
#define M_ (B_ * L_)          // 16384 rows
#define LN_EPS 1e-5f
#define SCAN_EPS 1e-8f
#define CT 64                 // scan chunk length == GEMM wave row-span
#define NC (L_ / CT)          // 64 chunks per sequence

typedef float f32x4 __attribute__((ext_vector_type(4)));
typedef short bf16x8 __attribute__((ext_vector_type(8)));   // 8 bf16 (4 VGPRs)

__device__ __forceinline__ void gload_lds16(const void* g, void* l) {
    __builtin_amdgcn_global_load_lds(
        (const __attribute__((address_space(1))) void*)g,
        (__attribute__((address_space(3))) void*)l, 16, 0, 0);
}

__device__ __forceinline__ float bf2f(unsigned short u) {
    return __uint_as_float((unsigned)u << 16);
}

// ---------------------------------------------------------------------------
// Fused LayerNorm (blocks [0, M_)) + weight bf16 conversion (tail blocks).
// LN: one block (256 thr) per row of 1024; single fused sum/sumsq reduction.
// ---------------------------------------------------------------------------
__global__ __launch_bounds__(256) void ln_cvt_kernel(
    const float* __restrict__ X, const float* __restrict__ gamma,
    const float* __restrict__ beta, __hip_bfloat16* __restrict__ Zb,
    const float* __restrict__ Wa, const float* __restrict__ Wb,
    const float* __restrict__ Wc, __hip_bfloat16* __restrict__ Wbf)
{
    const int tid = threadIdx.x;
    if (blockIdx.x >= M_) {
        // weight conversion tail: 1536 blocks x 256 thr x 8 elems
        const int gid = (blockIdx.x - M_) * 256 + tid;
        const size_t i = (size_t)gid * 8;
        const int which = (int)(i >> 20);
        const size_t off = i & ((1ull << 20) - 1);
        const float* W = (which == 0) ? Wa : (which == 1) ? Wb : Wc;
        float4 v0 = *reinterpret_cast<const float4*>(W + off);
        float4 v1 = *reinterpret_cast<const float4*>(W + off + 4);
        union { bf16x8 v; __hip_bfloat16 h[8]; } pk;
        pk.h[0] = __float2bfloat16(v0.x); pk.h[1] = __float2bfloat16(v0.y);
        pk.h[2] = __float2bfloat16(v0.z); pk.h[3] = __float2bfloat16(v0.w);
        pk.h[4] = __float2bfloat16(v1.x); pk.h[5] = __float2bfloat16(v1.y);
        pk.h[6] = __float2bfloat16(v1.z); pk.h[7] = __float2bfloat16(v1.w);
        *reinterpret_cast<bf16x8*>(Wbf + i) = pk.v;
        return;
    }

    const int row = blockIdx.x;
    const float* x = X + (size_t)row * D_;

    float4 v = *reinterpret_cast<const float4*>(x + tid * 4);
    float s = v.x + v.y + v.z + v.w;
    float q = v.x * v.x + v.y * v.y + v.z * v.z + v.w * v.w;
    #pragma unroll
    for (int off = 32; off > 0; off >>= 1) {
        s += __shfl_down(s, off);
        q += __shfl_down(q, off);
    }

    __shared__ float red[8];
    const int wid = tid >> 6, lane = tid & 63;
    if (lane == 0) { red[wid] = s; red[4 + wid] = q; }
    __syncthreads();
    const float mean = (red[0] + red[1] + red[2] + red[3]) * (1.0f / D_);
    const float ex2  = (red[4] + red[5] + red[6] + red[7]) * (1.0f / D_);
    const float var  = ex2 - mean * mean;
    const float rs = rsqrtf(var + LN_EPS);

    float4 g  = *reinterpret_cast<const float4*>(gamma + tid * 4);
    float4 be = *reinterpret_cast<const float4*>(beta + tid * 4);
    union { ushort4 u4; __hip_bfloat16 h[4]; } pk;
    pk.h[0] = __float2bfloat16((v.x - mean) * rs * g.x + be.x);
    pk.h[1] = __float2bfloat16((v.y - mean) * rs * g.y + be.y);
    pk.h[2] = __float2bfloat16((v.z - mean) * rs * g.z + be.z);
    pk.h[3] = __float2bfloat16((v.w - mean) * rs * g.w + be.w);
    *reinterpret_cast<ushort4*>(Zb + (size_t)row * D_ + tid * 4) = pk.u4;
}

// ---------------------------------------------------------------------------
// Fused triple GEMM via bf16 MFMA. 128x128 tile, BK=32, 2-phase double-
// buffered LDS: STAGE(t+1) issued BEFORE ds_read+MFMA of t, ONE barrier per
// K-step (loads stay in flight under compute). XOR chunk-swizzled LDS (0
// bank conflicts, measured r4/r6). XCD-aware bijective block swizzle.
// Outputs bf16; gate tile also emits per-64-row-chunk products (LP).
// ---------------------------------------------------------------------------
#define TM 128
#define TN 128
#define TK 32
#define NKS (D_ / TK)   // 32 K-steps

__global__ __launch_bounds__(256) void gemm3_mfma(
    const __hip_bfloat16* __restrict__ Zb, const __hip_bfloat16* __restrict__ Wbf,
    const float* __restrict__ ba, const float* __restrict__ bb, const float* __restrict__ bc,
    __hip_bfloat16* __restrict__ Aout, __hip_bfloat16* __restrict__ Bxout,
    __hip_bfloat16* __restrict__ Cout, float* __restrict__ LP)
{
    __shared__ __hip_bfloat16 As[2][TM * TK];   // 2 x 8 KB
    __shared__ __hip_bfloat16 Bs[2][TN * TK];   // 2 x 8 KB

    const int tid  = threadIdx.x;
    const int wv   = tid >> 6;
    const int lane = tid & 63;
    const int wr   = wv >> 1, wc = wv & 1;

    // XCD-aware swizzle: 3072 blocks, 8 XCDs, 384 contiguous per XCD.
    // Within an XCD, n-tile varies fastest -> 24 neighbors share one Z panel.
    const int braw = blockIdx.x;
    const int bid  = (braw & 7) * 384 + (braw >> 3);
    const int nb   = bid % 24;
    const int mb   = bid / 24;
    const int m0   = mb * TM;
    const int n0g  = nb * TN;
    const int which = n0g >> 10;
    const int n0   = n0g & 1023;

    const __hip_bfloat16* __restrict__ Wsrc = Wbf + ((size_t)which << 20);
    const float* __restrict__ bias = (which == 0) ? ba : (which == 1) ? bb : bc;

    // Staging: chunk c (16B) at LDS bytes c*16; row=c>>2, ci=c&3.
    // Swizzle: slot(row,ci) holds global chunk ci ^ ((row>>1)&3).
    const int c0 = tid, c1 = 256 + tid;
    const int row0 = c0 >> 2, sc0 = (c0 & 3) ^ ((row0 >> 1) & 3);
    const int row1 = c1 >> 2, sc1 = (c1 & 3) ^ ((row1 >> 1) & 3);
    const int dOff0 = (wv * 64) * 8;          // wave-uniform LDS chunk offsets
    const int dOff1 = (256 + wv * 64) * 8;
    const __hip_bfloat16* zSrc0 = Zb + (size_t)(m0 + row0) * D_ + sc0 * 8;
    const __hip_bfloat16* zSrc1 = Zb + (size_t)(m0 + row1) * D_ + sc1 * 8;
    const __hip_bfloat16* wSrc0 = Wsrc + (size_t)(n0 + row0) * D_ + sc0 * 8;
    const __hip_bfloat16* wSrc1 = Wsrc + (size_t)(n0 + row1) * D_ + sc1 * 8;

    f32x4 acc[4][4] = {};
    const int rl = lane & 15, kg = lane >> 4;

    // prologue: stage K-step 0 into buf 0
    gload_lds16(zSrc0, &As[0][dOff0]);
    gload_lds16(zSrc1, &As[0][dOff1]);
    gload_lds16(wSrc0, &Bs[0][dOff0]);
    gload_lds16(wSrc1, &Bs[0][dOff1]);
    __syncthreads();

    int cur = 0;
    for (int t = 0; t < NKS; ++t) {
        // phase A: issue next tile's loads into the other buffer
        if (t < NKS - 1) {
            const int k1 = (t + 1) * TK;
            gload_lds16(zSrc0 + k1, &As[cur ^ 1][dOff0]);
            gload_lds16(zSrc1 + k1, &As[cur ^ 1][dOff1]);
            gload_lds16(wSrc0 + k1, &Bs[cur ^ 1][dOff0]);
            gload_lds16(wSrc1 + k1, &Bs[cur ^ 1][dOff1]);
        }
        // phase B: compute current buffer (compiler inserts lgkmcnt waits)
        bf16x8 af[4], bfr[4];
        const char* aBase = reinterpret_cast<const char*>(As[cur]);
        const char* bBase = reinterpret_cast<const char*>(Bs[cur]);
        #pragma unroll
        for (int i = 0; i < 4; ++i) {
            const int ra = wr * 64 + i * 16 + rl;
            af[i] = *reinterpret_cast<const bf16x8*>(
                aBase + ra * 64 + ((kg ^ ((ra >> 1) & 3)) << 4));
            const int rb = wc * 64 + i * 16 + rl;
            bfr[i] = *reinterpret_cast<const bf16x8*>(
                bBase + rb * 64 + ((kg ^ ((rb >> 1) & 3)) << 4));
        }
        #pragma unroll
        for (int i = 0; i < 4; ++i)
            #pragma unroll
            for (int j = 0; j < 4; ++j)
                acc[i][j] = __builtin_amdgcn_mfma_f32_16x16x32_bf16(
                    af[i], bfr[j], acc[i][j], 0, 0, 0);
        // one barrier per K-step: drains vmcnt (next buf ready) and protects
        // cur (everyone finished reading) before it is overwritten at t+1.
        __syncthreads();
        cur ^= 1;
    }

    const int cn = n0 + wc * 64 + rl;
    float bj[4];
    #pragma unroll
    for (int j = 0; j < 4; ++j) bj[j] = bias[cn + j * 16];

    if (which == 0) {
        // Gate A: sigmoid -> bf16 store; chunk product from the SAME
        // bf16-rounded values the scan reads (wave rows == one 64-chunk).
        float pp[4] = {1.0f, 1.0f, 1.0f, 1.0f};
        #pragma unroll
        for (int i = 0; i < 4; ++i) {
            #pragma unroll
            for (int r = 0; r < 4; ++r) {
                const int m = m0 + wr * 64 + i * 16 + kg * 4 + r;
                __hip_bfloat16* dst = Aout + (size_t)m * D_ + cn;
                #pragma unroll
                for (int j = 0; j < 4; ++j) {
                    const float val = 1.0f / (1.0f + expf(-(acc[i][j][r] + bj[j])));
                    const __hip_bfloat16 hb = __float2bfloat16(val);
                    dst[j * 16] = hb;
                    pp[j] *= __bfloat162float(hb);
                }
            }
        }
        #pragma unroll
        for (int j = 0; j < 4; ++j) {
            pp[j] *= __shfl_xor(pp[j], 16);
            pp[j] *= __shfl_xor(pp[j], 32);
        }
        const float sel = (kg == 0) ? pp[0] : (kg == 1) ? pp[1] : (kg == 2) ? pp[2] : pp[3];
        const int bseq = m0 >> 12;                 // sequence index
        const int cidx = ((m0 & 4095) >> 6) + wr;  // chunk index within sequence
        LP[((size_t)bseq * NC + cidx) * D_ + n0 + wc * 64 + kg * 16 + rl] = sel;
    } else {
        __hip_bfloat16* __restrict__ Out = (which == 1) ? Bxout : Cout;
        #pragma unroll
        for (int i = 0; i < 4; ++i) {
            #pragma unroll
            for (int r = 0; r < 4; ++r) {
                const int m = m0 + wr * 64 + i * 16 + kg * 4 + r;
                __hip_bfloat16* dst = Out + (size_t)m * D_ + cn;
                #pragma unroll
                for (int j = 0; j < 4; ++j)
                    dst[j * 16] = __float2bfloat16(acc[i][j][r] + bj[j]);
            }
        }
    }
}

// ---------------------------------------------------------------------------
// Chunked scan on bf16 A/Bx/C (fp32 arithmetic, exact eps/underflow
// semantics). Big kernels: 2 channels per thread (ushort2/float2 loads).
// ---------------------------------------------------------------------------
__global__ __launch_bounds__(128) void scan_chunkpfx(
    const float* __restrict__ LP, float* __restrict__ Pstart)
{
    const int ch = blockIdx.x * 128 + threadIdx.x;  // 4096 channels
    const int e = ch & (D_ - 1);
    const int b = ch >> 10;
    const size_t base = (size_t)b * NC * D_ + e;
    float p = 1.0f;
    #pragma unroll 8
    for (int c = 0; c < NC; ++c) {
        Pstart[base + (size_t)c * D_] = p;
        p *= LP[base + (size_t)c * D_];
    }
}

__global__ __launch_bounds__(128) void scan_chunksum(
    const __hip_bfloat16* __restrict__ A, const __hip_bfloat16* __restrict__ Bx,
    const float* __restrict__ Pstart, float* __restrict__ Ssum)
{
    const int blk = blockIdx.x;                     // 1024 blocks
    const int eg = blk & 3, c = (blk >> 2) & (NC - 1), b = blk >> 8;
    const int e = eg * 256 + threadIdx.x * 2;
    size_t base = ((size_t)b * L_ + (size_t)c * CT) * D_ + e;
    const size_t chid = ((size_t)b * NC + c) * D_ + e;
    float2 pst = *reinterpret_cast<const float2*>(Pstart + chid);
    float p0 = pst.x, p1 = pst.y, s0 = 0.0f, s1 = 0.0f;
    #pragma unroll 4
    for (int t = 0; t < CT; ++t) {
        const size_t idx = base + (size_t)t * D_;
        ushort2 a  = *reinterpret_cast<const ushort2*>(A + idx);
        ushort2 bx = *reinterpret_cast<const ushort2*>(Bx + idx);
        p0 *= bf2f(a.x);  p1 *= bf2f(a.y);
        s0 += bf2f(bx.x) / (p0 + SCAN_EPS);
        s1 += bf2f(bx.y) / (p1 + SCAN_EPS);
    }
    *reinterpret_cast<float2*>(Ssum + chid) = make_float2(s0, s1);
}

__global__ __launch_bounds__(128) void scan_sumpfx(
    const float* __restrict__ Ssum, float* __restrict__ Sstart)
{
    const int ch = blockIdx.x * 128 + threadIdx.x;  // 4096 channels
    const int e = ch & (D_ - 1);
    const int b = ch >> 10;
    const size_t base = (size_t)b * NC * D_ + e;
    float s = 0.0f;
    #pragma unroll 8
    for (int c = 0; c < NC; ++c) {
        Sstart[base + (size_t)c * D_] = s;
        s += Ssum[base + (size_t)c * D_];
    }
}

__global__ __launch_bounds__(128) void scan_final(
    const __hip_bfloat16* __restrict__ A, const __hip_bfloat16* __restrict__ Bx,
    const __hip_bfloat16* __restrict__ C, const float* __restrict__ X,
    const float* __restrict__ Pstart, const float* __restrict__ Sstart,
    const float* __restrict__ h0, float* __restrict__ out)
{
    const int blk = blockIdx.x;                     // 1024 blocks
    const int eg = blk & 3, c = (blk >> 2) & (NC - 1), b = blk >> 8;
    const int e = eg * 256 + threadIdx.x * 2;
    size_t base = ((size_t)b * L_ + (size_t)c * CT) * D_ + e;
    const size_t chid = ((size_t)b * NC + c) * D_ + e;
    float2 pst = *reinterpret_cast<const float2*>(Pstart + chid);
    float2 sst = *reinterpret_cast<const float2*>(Sstart + chid);
    float2 h02 = *reinterpret_cast<const float2*>(h0 + e);
    float p0 = pst.x, p1 = pst.y, s0 = sst.x, s1 = sst.y;
    #pragma unroll 4
    for (int t = 0; t < CT; ++t) {
        const size_t idx = base + (size_t)t * D_;
        ushort2 a  = *reinterpret_cast<const ushort2*>(A + idx);
        ushort2 bx = *reinterpret_cast<const ushort2*>(Bx + idx);
        ushort2 cc = *reinterpret_cast<const ushort2*>(C + idx);
        float2 x   = *reinterpret_cast<const float2*>(X + idx);
        p0 *= bf2f(a.x);  p1 *= bf2f(a.y);
        s0 += bf2f(bx.x) / (p0 + SCAN_EPS);
        s1 += bf2f(bx.y) / (p1 + SCAN_EPS);
        const float o0 = fmaf(bf2f(cc.x), p0 * (h02.x + s0), x.x);
        const float o1 = fmaf(bf2f(cc.y), p1 * (h02.y + s1), x.y);
        *reinterpret_cast<float2*>(out + idx) = make_float2(o0, o1);
    }
}

// ---------------------------------------------------------------------------
extern "C" void kernel_launch(void* const* d_in, const int* in_sizes, int n_in,
                              void* d_out, int out_size, void* d_ws, size_t ws_size,
                              hipStream_t stream)
{
    const float* X     = (const float*)d_in[0];
    const float* Wa    = (const float*)d_in[1];
    const float* ba    = (const float*)d_in[2];
    const float* Wb    = (const float*)d_in[3];
    const float* bb    = (const float*)d_in[4];
    const float* Wc    = (const float*)d_in[5];
    const float* bc    = (const float*)d_in[6];
    const float* gamma = (const float*)d_in[7];
    const float* beta  = (const float*)d_in[8];
    const float* h0    = (const float*)d_in[9];
    float* out = (float*)d_out;

    const size_t NELT = (size_t)M_ * D_;        // 16,777,216
    const size_t NCH  = (size_t)B_ * NC * D_;   // 262,144

    __hip_bfloat16* Zb   = (__hip_bfloat16*)d_ws;           // 32 MB
    __hip_bfloat16* Wbf  = Zb + NELT;                        // 6 MB
    __hip_bfloat16* Abf  = Wbf + 3ull * 1024 * 1024;         // 32 MB
    __hip_bfloat16* Bxbf = Abf + NELT;                       // 32 MB
    __hip_bfloat16* Cbf  = Bxbf + NELT;                      // 32 MB
    float* LP   = (float*)(Cbf + NELT);                      // 1 MB
    float* Pst  = LP   + NCH;
    float* Ssum = Pst  + NCH;
    float* Sst  = Ssum + NCH;
    (void)ws_size; (void)in_sizes; (void)n_in; (void)out_size;

    // 1. LayerNorm + weight bf16 conversion (single fused launch)
    ln_cvt_kernel<<<M_ + 1536, 256, 0, stream>>>(X, gamma, beta, Zb, Wa, Wb, Wc, Wbf);

    // 2. Fused triple GEMM (2-phase dbuf, XCD swizzle); emits LP too.
    gemm3_mfma<<<3072, 256, 0, stream>>>(
        Zb, Wbf, ba, bb, bc, Abf, Bxbf, Cbf, LP);

    // 3. Chunked scan (exact reference semantics)
    scan_chunkpfx<<<32, 128, 0, stream>>>(LP, Pst);
    scan_chunksum<<<1024, 128, 0, stream>>>(Abf, Bxbf, Pst, Ssum);
    scan_sumpfx<<<32, 128, 0, stream>>>(Ssum, Sst);
    scan_final<<<1024, 128, 0, stream>>>(Abf, Bxbf, Cbf, X, Pst, Sst, h0, out);
}